// Round 5
// baseline (814.549 us; speedup 1.0000x reference)
//
#include <hip/hip_runtime.h>

#define BS   8192
#define DIM  1024
#define TINV 10.0f    // 1 / TEMPERATURE
#define MARGIN 1.0f   // max(0.01, 1.0 - 0.1*0.0)

#define BM  128
#define BN  128
#define BKB 128       // fp8 K-bytes per staging iteration (16x16x128 MFMA)

// fp8 values are the normalized elements scaled by 16 -> dot = 256 * cos
#define QSCALE   16.0f
#define INV_QSQ  (1.0f / 256.0f)

typedef __attribute__((ext_vector_type(4))) float f32x4;
typedef __attribute__((ext_vector_type(4))) int   int4v;
typedef __attribute__((ext_vector_type(8))) int   int8v;

// ---------------- Kernel 1: L2-normalize rows, emit fp8(e4m3,x16) + posdist -
// (unchanged — one wave per row, pure shfl reduction)
__global__ __launch_bounds__(256) void normalize_kernel(
    const float* __restrict__ feat,
    unsigned char* __restrict__ Afp8,
    unsigned char* __restrict__ Nfp8,
    float* __restrict__ posdist)
{
    const int lane = threadIdx.x & 63;
    const int row  = blockIdx.x * 4 + (threadIdx.x >> 6);   // wave = row

    const float4* fo = (const float4*)(feat + (size_t)row * DIM);
    const float4* fp = (const float4*)(feat + (size_t)(BS + row) * DIM);
    const float4* fn = (const float4*)(feat + (size_t)(2 * BS + row) * DIM);

    float4 o[4], p[4], n[4];
    #pragma unroll
    for (int k = 0; k < 4; k++) {
        o[k] = fo[lane + 64 * k];
        p[k] = fp[lane + 64 * k];
        n[k] = fn[lane + 64 * k];
    }

    float so = 0.f, sp = 0.f, sn = 0.f;
    #pragma unroll
    for (int k = 0; k < 4; k++) {
        so += o[k].x*o[k].x + o[k].y*o[k].y + o[k].z*o[k].z + o[k].w*o[k].w;
        sp += p[k].x*p[k].x + p[k].y*p[k].y + p[k].z*p[k].z + p[k].w*p[k].w;
        sn += n[k].x*n[k].x + n[k].y*n[k].y + n[k].z*n[k].z + n[k].w*n[k].w;
    }
    #pragma unroll
    for (int off = 1; off < 64; off <<= 1) {
        so += __shfl_xor(so, off);
        sp += __shfl_xor(sp, off);
        sn += __shfl_xor(sn, off);
    }

    const float io  = 1.0f / fmaxf(sqrtf(so), 1e-12f);
    const float ip  = 1.0f / fmaxf(sqrtf(sp), 1e-12f);
    const float in_ = 1.0f / fmaxf(sqrtf(sn), 1e-12f);

    int* Ar = (int*)(Afp8 + (size_t)row * DIM);
    int* Nr = (int*)(Nfp8 + (size_t)row * DIM);

    float d = 0.f;
    #pragma unroll
    for (int k = 0; k < 4; k++) {
        float ax = o[k].x*io, ay = o[k].y*io, az = o[k].z*io, aw = o[k].w*io;
        float nx = n[k].x*in_, ny = n[k].y*in_, nz = n[k].z*in_, nw = n[k].w*in_;
        int pa = __builtin_amdgcn_cvt_pk_fp8_f32(ax*QSCALE, ay*QSCALE, 0, false);
        pa     = __builtin_amdgcn_cvt_pk_fp8_f32(az*QSCALE, aw*QSCALE, pa, true);
        int pn = __builtin_amdgcn_cvt_pk_fp8_f32(nx*QSCALE, ny*QSCALE, 0, false);
        pn     = __builtin_amdgcn_cvt_pk_fp8_f32(nz*QSCALE, nw*QSCALE, pn, true);
        Ar[lane + 64 * k] = pa;      // coalesced 4B stores
        Nr[lane + 64 * k] = pn;
        float dx = ax - p[k].x*ip, dy = ay - p[k].y*ip;
        float dz = az - p[k].z*ip, dw = aw - p[k].w*ip;
        d += dx*dx + dy*dy + dz*dz + dw*dw;
    }
    #pragma unroll
    for (int off = 1; off < 64; off <<= 1) d += __shfl_xor(d, off);
    if (lane == 0) posdist[row] = d * TINV;
}

// Load one 32B fragment from swizzled LDS: lo chunk at `off`, hi at off^16
// (chunk parity: (q2+1)^x == (q2^x)^1 for even q2). Union avoids repack.
__device__ __forceinline__ int8v ld_frag(const unsigned char* __restrict__ p,
                                         int off) {
    union { int8v v; struct { int4v lo, hi; } s; } u;
    u.s.lo = *(const int4v*)(p + off);
    u.s.hi = *(const int4v*)(p + (off ^ 16));
    return u.v;
}

// ---------------- Kernel 2: MX-fp8 16x16x128 MFMA max-GEMM (R15) ------------
// R15 = R13 tile (64x64 wave, 128x128 block, validated absmax=0) with the
// register problem fixed. R13 post-mortem: compiler allocated 232 VGPR
// (essential live ~104: acc 64 + A-frags 32 + 1 B-frag 8) -> 1 block/CU,
// 11.6% occupancy, 164 us — every barrier drain exposed, same failure as
// R11. Fix: (a) __launch_bounds__(256,3) caps allocator at ~170 VGPR,
// forcing 3 waves/SIMD (3 blocks/CU, the regime that made R9 work);
// (b) hoist 4 A-frags once, STREAM B-frags one at a time (j-outer,
// i-inner) so peak liveness is structurally ~104+addr.
// Arithmetic: LDS pipe 2.10M b128 x 16 cyc / 256 CU = 55 us floor (R9:
// 82 us); MFMA floor 29.5 us; predict 70-85 us at R9-quality overlap.
__global__ __launch_bounds__(256, 3) void maxgemm_kernel(
    const unsigned char* __restrict__ Afp8,
    const unsigned char* __restrict__ Nfp8,
    float* __restrict__ partial)   // [BS][128] row-major
{
    __shared__ unsigned char As[BM * BKB];   // 16 KiB
    __shared__ unsigned char Bs[BN * BKB];   // 16 KiB

    const int tid  = threadIdx.x;
    const int lane = tid & 63;
    const int w    = tid >> 6;      // wave 0..3
    const int wr   = w >> 1;        // wave-row: owns 64 output rows
    const int wc   = w & 1;         // wave-col: owns 64 output cols
    const int rowBase = blockIdx.y * BM;
    const int colBase = blockIdx.x * BN;

    const int lrow = lane >> 3;                      // 0..7: row in 8-row slab
    const int gcol = ((lane & 7) ^ lrow) * 16;       // swizzled 16B chunk (bytes)

    const unsigned char* Ag = Afp8 + (size_t)rowBase * DIM;
    const unsigned char* Bg = Nfp8 + (size_t)colBase * DIM;

    const int q2   = (lane >> 4) * 2;                // first 16B chunk of quad
    const int arow = wr * 64 + (lane & 15);          // + i*16, i=0..3
    const int brow = wc * 64 + (lane & 15);          // + j*16, j=0..3
    const int aoff = arow * BKB + ((q2 ^ (arow & 7)) << 4);
    const int boff = brow * BKB + ((q2 ^ (brow & 7)) << 4);

    f32x4 acc[4][4];
    #pragma unroll
    for (int i = 0; i < 4; i++)
        #pragma unroll
        for (int j = 0; j < 4; j++)
            acc[i][j] = (f32x4){0.f, 0.f, 0.f, 0.f};

    for (int k0 = 0; k0 < DIM; k0 += BKB) {
        __syncthreads();  // prior iter's LDS reads done
        #pragma unroll
        for (int c = 0; c < 4; c++) {               // A: 4 slabs of 8 rows/wave
            const int r0 = w * 32 + c * 8;
            __builtin_amdgcn_global_load_lds(
                (const __attribute__((address_space(1))) void*)
                    (Ag + (size_t)(r0 + lrow) * DIM + k0 + gcol),
                (__attribute__((address_space(3))) void*)(As + r0 * BKB),
                16, 0, 0);
        }
        #pragma unroll
        for (int c = 0; c < 4; c++) {               // B: 4 slabs of 8 rows/wave
            const int r0 = w * 32 + c * 8;
            __builtin_amdgcn_global_load_lds(
                (const __attribute__((address_space(1))) void*)
                    (Bg + (size_t)(r0 + lrow) * DIM + k0 + gcol),
                (__attribute__((address_space(3))) void*)(Bs + r0 * BKB),
                16, 0, 0);
        }
        __syncthreads();  // vmcnt drained by barrier semantics

        // A-frags resident (32 regs), B-frags streamed one at a time.
        int8v af[4];
        #pragma unroll
        for (int i = 0; i < 4; i++)
            af[i] = ld_frag(As, aoff + i * 16 * BKB);

        #pragma unroll
        for (int j = 0; j < 4; j++) {
            const int8v b = ld_frag(Bs, boff + j * 16 * BKB);
            #pragma unroll
            for (int i = 0; i < 4; i++)
                acc[i][j] = __builtin_amdgcn_mfma_scale_f32_16x16x128_f8f6f4(
                    af[i], b, acc[i][j],
                    0, 0,               // cbsz=FP8(e4m3), blgp=FP8(e4m3)
                    0, 0x7F7F7F7F,      // opselA, scaleA = 1.0
                    0, 0x7F7F7F7F);     // opselB, scaleB = 1.0
        }
    }

    // Epilogue: per-row max over this wave's 64 columns.
    // C/D layout (m89/m91): col = lane&15, row = (lane>>4)*4 + reg.
    const int stripe = blockIdx.x * 2 + wc;          // 64-col stripe index
    #pragma unroll
    for (int i = 0; i < 4; i++) {
        #pragma unroll
        for (int r = 0; r < 4; r++) {
            float v = fmaxf(fmaxf(acc[i][0][r], acc[i][1][r]),
                            fmaxf(acc[i][2][r], acc[i][3][r]));
            v = fmaxf(v, __shfl_xor(v, 1));
            v = fmaxf(v, __shfl_xor(v, 2));
            v = fmaxf(v, __shfl_xor(v, 4));
            v = fmaxf(v, __shfl_xor(v, 8));
            if ((lane & 15) == 0) {
                const int row = rowBase + wr * 64 + i * 16 + (lane >> 4) * 4 + r;
                partial[(size_t)row * 128 + stripe] = v;   // = 256 * cos
            }
        }
    }
}

// ---------------- Kernel 3: stripe-max -> loss terms -> per-block partials --
__global__ __launch_bounds__(256) void reduce_kernel(
    const float* __restrict__ partial,
    const float* __restrict__ posdist,
    float* __restrict__ blockpart)   // [256][3]
{
    const int tid  = threadIdx.x;
    const int lane = tid & 63;
    const int w    = tid >> 6;
    __shared__ float red[4][3];

    float sloss = 0.f, spos = 0.f, shard = 0.f;

    #pragma unroll
    for (int i = 0; i < 8; i++) {
        const int row = blockIdx.x * 32 + w * 8 + i;
        float v = fmaxf(partial[(size_t)row * 128 + lane],
                        partial[(size_t)row * 128 + 64 + lane]);
        #pragma unroll
        for (int off = 1; off < 64; off <<= 1) v = fmaxf(v, __shfl_xor(v, off));
        if (lane == 0) {
            // v = 256*cos  ->  hard = (2 - 2*cos)/T = (2 - v/128)*TINV
            const float hard = (2.0f - 2.0f * v * INV_QSQ) * TINV;
            const float pos  = posdist[row];
            sloss += fmaxf(MARGIN + pos - hard, 0.0f);
            spos  += pos;
            shard += hard;
        }
    }
    if (lane == 0) { red[w][0] = sloss; red[w][1] = spos; red[w][2] = shard; }
    __syncthreads();
    if (tid == 0) {
        #pragma unroll
        for (int k = 0; k < 3; k++)
            blockpart[blockIdx.x * 3 + k] =
                red[0][k] + red[1][k] + red[2][k] + red[3][k];
    }
}

// ---------------- Kernel 4: finalize means (one wave, no atomics) -----------
__global__ __launch_bounds__(64) void finalize_kernel(
    const float* __restrict__ blockpart,
    float* __restrict__ out)
{
    const int lane = threadIdx.x;
    float a = 0.f, b = 0.f, c = 0.f;
    #pragma unroll
    for (int m = 0; m < 4; m++) {
        a += blockpart[(lane + 64 * m) * 3 + 0];
        b += blockpart[(lane + 64 * m) * 3 + 1];
        c += blockpart[(lane + 64 * m) * 3 + 2];
    }
    #pragma unroll
    for (int off = 1; off < 64; off <<= 1) {
        a += __shfl_xor(a, off);
        b += __shfl_xor(b, off);
        c += __shfl_xor(c, off);
    }
    if (lane == 0) {
        const float inv = 1.0f / (float)BS;
        out[0] = a * inv;
        out[1] = b * inv;
        out[2] = c * inv;
    }
}

extern "C" void kernel_launch(void* const* d_in, const int* in_sizes, int n_in,
                              void* d_out, int out_size, void* d_ws, size_t ws_size,
                              hipStream_t stream) {
    const float* feat = (const float*)d_in[0];
    char* ws = (char*)d_ws;

    // ws layout: Afp8 8MiB | Nfp8 8MiB | partial 4MiB | posdist 32KiB | blockpart
    unsigned char* Afp8      = (unsigned char*)ws;
    unsigned char* Nfp8      = (unsigned char*)(ws + ((size_t)8 << 20));
    float*         partial   = (float*)(ws + ((size_t)16 << 20));
    float*         posdist   = (float*)(ws + ((size_t)20 << 20));
    float*         blockpart = (float*)(ws + ((size_t)20 << 20) + 32768);

    normalize_kernel<<<BS / 4, 256, 0, stream>>>(feat, Afp8, Nfp8, posdist);

    maxgemm_kernel<<<dim3(BS / BN, BS / BM), 256, 0, stream>>>(Afp8, Nfp8, partial);

    reduce_kernel<<<256, 256, 0, stream>>>(partial, posdist, blockpart);
    finalize_kernel<<<1, 64, 0, stream>>>(blockpart, (float*)d_out);
}

// Round 6
// 293.109 us; speedup vs baseline: 2.7790x; 2.7790x over previous
//
#include <hip/hip_runtime.h>

#define BS   8192
#define DIM  1024
#define TINV 10.0f    // 1 / TEMPERATURE
#define MARGIN 1.0f   // max(0.01, 1.0 - 0.1*0.0)

#define BM  128
#define BN  64
#define BKB 128       // fp8 K-bytes per staging iteration (16x16x128 MFMA)

// fp8 values are the normalized elements scaled by 16 -> dot = 256 * cos
#define QSCALE   16.0f
#define INV_QSQ  (1.0f / 256.0f)

typedef __attribute__((ext_vector_type(4))) float f32x4;
typedef __attribute__((ext_vector_type(4))) int   int4v;
typedef __attribute__((ext_vector_type(8))) int   int8v;

// ---------------- Kernel 1: L2-normalize rows, emit fp8(e4m3,x16) + posdist -
// (unchanged — one wave per row, pure shfl reduction)
__global__ __launch_bounds__(256) void normalize_kernel(
    const float* __restrict__ feat,
    unsigned char* __restrict__ Afp8,
    unsigned char* __restrict__ Nfp8,
    float* __restrict__ posdist)
{
    const int lane = threadIdx.x & 63;
    const int row  = blockIdx.x * 4 + (threadIdx.x >> 6);   // wave = row

    const float4* fo = (const float4*)(feat + (size_t)row * DIM);
    const float4* fp = (const float4*)(feat + (size_t)(BS + row) * DIM);
    const float4* fn = (const float4*)(feat + (size_t)(2 * BS + row) * DIM);

    float4 o[4], p[4], n[4];
    #pragma unroll
    for (int k = 0; k < 4; k++) {
        o[k] = fo[lane + 64 * k];
        p[k] = fp[lane + 64 * k];
        n[k] = fn[lane + 64 * k];
    }

    float so = 0.f, sp = 0.f, sn = 0.f;
    #pragma unroll
    for (int k = 0; k < 4; k++) {
        so += o[k].x*o[k].x + o[k].y*o[k].y + o[k].z*o[k].z + o[k].w*o[k].w;
        sp += p[k].x*p[k].x + p[k].y*p[k].y + p[k].z*p[k].z + p[k].w*p[k].w;
        sn += n[k].x*n[k].x + n[k].y*n[k].y + n[k].z*n[k].z + n[k].w*n[k].w;
    }
    #pragma unroll
    for (int off = 1; off < 64; off <<= 1) {
        so += __shfl_xor(so, off);
        sp += __shfl_xor(sp, off);
        sn += __shfl_xor(sn, off);
    }

    const float io  = 1.0f / fmaxf(sqrtf(so), 1e-12f);
    const float ip  = 1.0f / fmaxf(sqrtf(sp), 1e-12f);
    const float in_ = 1.0f / fmaxf(sqrtf(sn), 1e-12f);

    int* Ar = (int*)(Afp8 + (size_t)row * DIM);
    int* Nr = (int*)(Nfp8 + (size_t)row * DIM);

    float d = 0.f;
    #pragma unroll
    for (int k = 0; k < 4; k++) {
        float ax = o[k].x*io, ay = o[k].y*io, az = o[k].z*io, aw = o[k].w*io;
        float nx = n[k].x*in_, ny = n[k].y*in_, nz = n[k].z*in_, nw = n[k].w*in_;
        int pa = __builtin_amdgcn_cvt_pk_fp8_f32(ax*QSCALE, ay*QSCALE, 0, false);
        pa     = __builtin_amdgcn_cvt_pk_fp8_f32(az*QSCALE, aw*QSCALE, pa, true);
        int pn = __builtin_amdgcn_cvt_pk_fp8_f32(nx*QSCALE, ny*QSCALE, 0, false);
        pn     = __builtin_amdgcn_cvt_pk_fp8_f32(nz*QSCALE, nw*QSCALE, pn, true);
        Ar[lane + 64 * k] = pa;      // coalesced 4B stores
        Nr[lane + 64 * k] = pn;
        float dx = ax - p[k].x*ip, dy = ay - p[k].y*ip;
        float dz = az - p[k].z*ip, dw = aw - p[k].w*ip;
        d += dx*dx + dy*dy + dz*dz + dw*dw;
    }
    #pragma unroll
    for (int off = 1; off < 64; off <<= 1) d += __shfl_xor(d, off);
    if (lane == 0) posdist[row] = d * TINV;
}

// Load one 32B fragment from swizzled LDS: lo chunk at `off`, hi at off^16
// (chunk parity: (q2+1)^x == (q2^x)^1 for even q2). Union avoids repack.
__device__ __forceinline__ int8v ld_frag(const unsigned char* __restrict__ p,
                                         int off) {
    union { int8v v; struct { int4v lo, hi; } s; } u;
    u.s.lo = *(const int4v*)(p + off);
    u.s.hi = *(const int4v*)(p + (off ^ 16));
    return u.v;
}

// Load one 32B A-fragment straight from global (contiguous, no swizzle).
__device__ __forceinline__ int8v ld_glob(const unsigned char* __restrict__ p) {
    union { int8v v; struct { int4v lo, hi; } s; } u;
    u.s.lo = *(const int4v*)(p);
    u.s.hi = *(const int4v*)(p + 16);
    return u.v;
}

// ---------------- Kernel 2: MX-fp8 16x16x128 MFMA max-GEMM (R16) ------------
// R16 = R9 structure with A read DIRECTLY from global/L2 (no A staging).
// Insight: in this decomposition each A-frag is consumed by exactly ONE
// wave (wave w owns rows w*32..+31) — A's LDS staging was a pure
// pass-through (4/6 staging instrs, 4/12 b128 reads) with zero sharing.
// B (read 4x by all waves) stays in LDS. Counter model of R9: LDS pipe
// 12.3K b128/CU x 16 cyc = 197K of 264K cyc (75% busy, the binding
// resource; MfmaUtil 26%). Dropping A: 131K cyc -> 55 us LDS floor;
// A = 1.07 GB from L2 (~30 us @ 34.5 TB/s, latency hidden); LDS 24->8 KB
// so occupancy is VGPR-bound only (~5-6 blocks/CU at ~100 VGPR).
// R15 lesson: NO launch_bounds min-wave forcing (it spilled acc -> 2.8 GB
// scratch traffic, 725 us). R11/R13/R15 lesson: stay at 8 MFMA/iter —
// 16-MFMA bodies trigger compiler register inflation (232 VGPR).
__global__ __launch_bounds__(256) void maxgemm_kernel(
    const unsigned char* __restrict__ Afp8,
    const unsigned char* __restrict__ Nfp8,
    float* __restrict__ partial)   // [BS][128] row-major
{
    __shared__ unsigned char Bs[BN * BKB];   // 8 KiB (B only)

    const int tid  = threadIdx.x;
    const int lane = tid & 63;
    const int w    = tid >> 6;
    const int rowBase = blockIdx.y * BM;
    const int colBase = blockIdx.x * BN;

    const int lrow = lane >> 3;                      // 0..7: row in 8-row slab
    const int gcol = ((lane & 7) ^ lrow) * 16;       // swizzled 16B chunk (bytes)

    const unsigned char* Bg = Nfp8 + (size_t)colBase * DIM;

    // A: per-lane global base. Lane reads row (lane&15) of its wave's 32-row
    // strip, 32 contiguous bytes of K at segment (lane>>4)*32 — the exact
    // byte range the old LDS path delivered, now straight from L2.
    const unsigned char* Ap =
        Afp8 + (size_t)(rowBase + w * 32 + (lane & 15)) * DIM + ((lane >> 4) * 32);

    const int q2   = (lane >> 4) * 2;                // first 16B chunk of quad
    const int brow = (lane & 15);                    // + j*16, j=0..3
    const int boff = brow * BKB + ((q2 ^ (brow & 7)) << 4);

    f32x4 acc[2][4];
    #pragma unroll
    for (int i = 0; i < 2; i++)
        #pragma unroll
        for (int j = 0; j < 4; j++)
            acc[i][j] = (f32x4){0.f, 0.f, 0.f, 0.f};

    for (int k0 = 0; k0 < DIM; k0 += BKB) {
        __syncthreads();  // prior iter's Bs reads done
        #pragma unroll
        for (int s = 0; s < 2; s++) {               // B: 2 slabs of 8 rows/wave
            const int r0 = (w * 2 + s) * 8;
            __builtin_amdgcn_global_load_lds(
                (const __attribute__((address_space(1))) void*)
                    (Bg + (size_t)(r0 + lrow) * DIM + k0 + gcol),
                (__attribute__((address_space(3))) void*)(Bs + r0 * BKB),
                16, 0, 0);
        }
        // A frags straight from global — issued alongside B staging so both
        // latencies overlap; the barrier's vmcnt drain covers them together.
        const int8v a0 = ld_glob(Ap + k0);
        const int8v a1 = ld_glob(Ap + k0 + 16 * DIM);
        __syncthreads();  // vmcnt drained by barrier semantics: Bs ready

        int8v bf[4];
        #pragma unroll
        for (int j = 0; j < 4; j++)
            bf[j] = ld_frag(Bs, boff + j * 16 * BKB);

        #pragma unroll
        for (int j = 0; j < 4; j++)
            acc[0][j] = __builtin_amdgcn_mfma_scale_f32_16x16x128_f8f6f4(
                a0, bf[j], acc[0][j],
                0, 0,               // cbsz=FP8(e4m3), blgp=FP8(e4m3)
                0, 0x7F7F7F7F,      // opselA, scaleA = 1.0
                0, 0x7F7F7F7F);     // opselB, scaleB = 1.0
        #pragma unroll
        for (int j = 0; j < 4; j++)
            acc[1][j] = __builtin_amdgcn_mfma_scale_f32_16x16x128_f8f6f4(
                a1, bf[j], acc[1][j],
                0, 0,
                0, 0x7F7F7F7F,
                0, 0x7F7F7F7F);
    }

    // Epilogue: per-row max over this block's 64 columns (all in this wave).
    // C/D layout (m89/m91): col = lane&15, row = (lane>>4)*4 + reg.
    const int stripe = blockIdx.x;
    #pragma unroll
    for (int i = 0; i < 2; i++) {
        #pragma unroll
        for (int r = 0; r < 4; r++) {
            float v = fmaxf(fmaxf(acc[i][0][r], acc[i][1][r]),
                            fmaxf(acc[i][2][r], acc[i][3][r]));
            v = fmaxf(v, __shfl_xor(v, 1));
            v = fmaxf(v, __shfl_xor(v, 2));
            v = fmaxf(v, __shfl_xor(v, 4));
            v = fmaxf(v, __shfl_xor(v, 8));
            if ((lane & 15) == 0) {
                const int row = rowBase + w * 32 + i * 16 + (lane >> 4) * 4 + r;
                partial[(size_t)row * 128 + stripe] = v;   // = 256 * cos
            }
        }
    }
}

// ---------------- Kernel 3: stripe-max -> loss terms -> per-block partials --
// 256 blocks (was 64): full CU coverage for this latency-bound pass.
__global__ __launch_bounds__(256) void reduce_kernel(
    const float* __restrict__ partial,
    const float* __restrict__ posdist,
    float* __restrict__ blockpart)   // [256][3]
{
    const int tid  = threadIdx.x;
    const int lane = tid & 63;
    const int w    = tid >> 6;
    __shared__ float red[4][3];

    float sloss = 0.f, spos = 0.f, shard = 0.f;

    #pragma unroll
    for (int i = 0; i < 8; i++) {
        const int row = blockIdx.x * 32 + w * 8 + i;
        float v = fmaxf(partial[(size_t)row * 128 + lane],
                        partial[(size_t)row * 128 + 64 + lane]);
        #pragma unroll
        for (int off = 1; off < 64; off <<= 1) v = fmaxf(v, __shfl_xor(v, off));
        if (lane == 0) {
            // v = 256*cos  ->  hard = (2 - 2*cos)/T = (2 - v/128)*TINV
            const float hard = (2.0f - 2.0f * v * INV_QSQ) * TINV;
            const float pos  = posdist[row];
            sloss += fmaxf(MARGIN + pos - hard, 0.0f);
            spos  += pos;
            shard += hard;
        }
    }
    if (lane == 0) { red[w][0] = sloss; red[w][1] = spos; red[w][2] = shard; }
    __syncthreads();
    if (tid == 0) {
        #pragma unroll
        for (int k = 0; k < 3; k++)
            blockpart[blockIdx.x * 3 + k] =
                red[0][k] + red[1][k] + red[2][k] + red[3][k];
    }
}

// ---------------- Kernel 4: finalize means (one wave, no atomics) -----------
__global__ __launch_bounds__(64) void finalize_kernel(
    const float* __restrict__ blockpart,
    float* __restrict__ out)
{
    const int lane = threadIdx.x;
    float a = 0.f, b = 0.f, c = 0.f;
    #pragma unroll
    for (int m = 0; m < 4; m++) {
        a += blockpart[(lane + 64 * m) * 3 + 0];
        b += blockpart[(lane + 64 * m) * 3 + 1];
        c += blockpart[(lane + 64 * m) * 3 + 2];
    }
    #pragma unroll
    for (int off = 1; off < 64; off <<= 1) {
        a += __shfl_xor(a, off);
        b += __shfl_xor(b, off);
        c += __shfl_xor(c, off);
    }
    if (lane == 0) {
        const float inv = 1.0f / (float)BS;
        out[0] = a * inv;
        out[1] = b * inv;
        out[2] = c * inv;
    }
}

extern "C" void kernel_launch(void* const* d_in, const int* in_sizes, int n_in,
                              void* d_out, int out_size, void* d_ws, size_t ws_size,
                              hipStream_t stream) {
    const float* feat = (const float*)d_in[0];
    char* ws = (char*)d_ws;

    // ws layout: Afp8 8MiB | Nfp8 8MiB | partial 4MiB | posdist 32KiB | blockpart
    unsigned char* Afp8      = (unsigned char*)ws;
    unsigned char* Nfp8      = (unsigned char*)(ws + ((size_t)8 << 20));
    float*         partial   = (float*)(ws + ((size_t)16 << 20));
    float*         posdist   = (float*)(ws + ((size_t)20 << 20));
    float*         blockpart = (float*)(ws + ((size_t)20 << 20) + 32768);

    normalize_kernel<<<BS / 4, 256, 0, stream>>>(feat, Afp8, Nfp8, posdist);

    maxgemm_kernel<<<dim3(BS / BN, BS / BM), 256, 0, stream>>>(Afp8, Nfp8, partial);

    reduce_kernel<<<256, 256, 0, stream>>>(partial, posdist, blockpart);
    finalize_kernel<<<1, 64, 0, stream>>>(blockpart, (float*)d_out);
}

// Round 7
// 266.425 us; speedup vs baseline: 3.0573x; 1.1002x over previous
//
#include <hip/hip_runtime.h>

#define BS   8192
#define DIM  1024
#define TINV 10.0f    // 1 / TEMPERATURE
#define MARGIN 1.0f   // max(0.01, 1.0 - 0.1*0.0)

#define BM  128
#define BN  64
#define BKB 128       // fp8 K-bytes per staging iteration (16x16x128 MFMA)

// fp8 values are the normalized elements scaled by 16 -> dot = 256 * cos
#define QSCALE   16.0f
#define INV_QSQ  (1.0f / 256.0f)

typedef __attribute__((ext_vector_type(4))) float f32x4;
typedef __attribute__((ext_vector_type(4))) int   int4v;
typedef __attribute__((ext_vector_type(8))) int   int8v;

// ---------------- Kernel 1: L2-normalize rows, emit fp8(e4m3,x16) + posdist -
// (unchanged — one wave per row, pure shfl reduction)
__global__ __launch_bounds__(256) void normalize_kernel(
    const float* __restrict__ feat,
    unsigned char* __restrict__ Afp8,
    unsigned char* __restrict__ Nfp8,
    float* __restrict__ posdist)
{
    const int lane = threadIdx.x & 63;
    const int row  = blockIdx.x * 4 + (threadIdx.x >> 6);   // wave = row

    const float4* fo = (const float4*)(feat + (size_t)row * DIM);
    const float4* fp = (const float4*)(feat + (size_t)(BS + row) * DIM);
    const float4* fn = (const float4*)(feat + (size_t)(2 * BS + row) * DIM);

    float4 o[4], p[4], n[4];
    #pragma unroll
    for (int k = 0; k < 4; k++) {
        o[k] = fo[lane + 64 * k];
        p[k] = fp[lane + 64 * k];
        n[k] = fn[lane + 64 * k];
    }

    float so = 0.f, sp = 0.f, sn = 0.f;
    #pragma unroll
    for (int k = 0; k < 4; k++) {
        so += o[k].x*o[k].x + o[k].y*o[k].y + o[k].z*o[k].z + o[k].w*o[k].w;
        sp += p[k].x*p[k].x + p[k].y*p[k].y + p[k].z*p[k].z + p[k].w*p[k].w;
        sn += n[k].x*n[k].x + n[k].y*n[k].y + n[k].z*n[k].z + n[k].w*n[k].w;
    }
    #pragma unroll
    for (int off = 1; off < 64; off <<= 1) {
        so += __shfl_xor(so, off);
        sp += __shfl_xor(sp, off);
        sn += __shfl_xor(sn, off);
    }

    const float io  = 1.0f / fmaxf(sqrtf(so), 1e-12f);
    const float ip  = 1.0f / fmaxf(sqrtf(sp), 1e-12f);
    const float in_ = 1.0f / fmaxf(sqrtf(sn), 1e-12f);

    int* Ar = (int*)(Afp8 + (size_t)row * DIM);
    int* Nr = (int*)(Nfp8 + (size_t)row * DIM);

    float d = 0.f;
    #pragma unroll
    for (int k = 0; k < 4; k++) {
        float ax = o[k].x*io, ay = o[k].y*io, az = o[k].z*io, aw = o[k].w*io;
        float nx = n[k].x*in_, ny = n[k].y*in_, nz = n[k].z*in_, nw = n[k].w*in_;
        int pa = __builtin_amdgcn_cvt_pk_fp8_f32(ax*QSCALE, ay*QSCALE, 0, false);
        pa     = __builtin_amdgcn_cvt_pk_fp8_f32(az*QSCALE, aw*QSCALE, pa, true);
        int pn = __builtin_amdgcn_cvt_pk_fp8_f32(nx*QSCALE, ny*QSCALE, 0, false);
        pn     = __builtin_amdgcn_cvt_pk_fp8_f32(nz*QSCALE, nw*QSCALE, pn, true);
        Ar[lane + 64 * k] = pa;      // coalesced 4B stores
        Nr[lane + 64 * k] = pn;
        float dx = ax - p[k].x*ip, dy = ay - p[k].y*ip;
        float dz = az - p[k].z*ip, dw = aw - p[k].w*ip;
        d += dx*dx + dy*dy + dz*dz + dw*dw;
    }
    #pragma unroll
    for (int off = 1; off < 64; off <<= 1) d += __shfl_xor(d, off);
    if (lane == 0) posdist[row] = d * TINV;
}

// Load one 32B fragment from swizzled LDS: lo chunk at `off`, hi at off^16
// (chunk parity: (q2+1)^x == (q2^x)^1 for even q2). Union avoids repack.
__device__ __forceinline__ int8v ld_frag(const unsigned char* __restrict__ p,
                                         int off) {
    union { int8v v; struct { int4v lo, hi; } s; } u;
    u.s.lo = *(const int4v*)(p + off);
    u.s.hi = *(const int4v*)(p + (off ^ 16));
    return u.v;
}

// ---------------- Kernel 2: MX-fp8 16x16x128 MFMA max-GEMM (R17) ------------
// R17 = R9's compute loop VERBATIM (proven 108 us champion; 6 experiments
// bracket it as a balanced local optimum: more work/iter -> VGPR inflation
// [R11/R13: 228/232], less work/iter -> latency exposure [R16: 152 us],
// dbuf neutral [R12], occupancy forcing -> spill [R15]) with ONE epilogue
// fix: partial is now [stripe][row] (transposed). R9's [row][stripe]
// layout wrote 4B per 128B line from 32 different blocks/XCDs ->
// WRITE_SIZE 32.8 MB for a 4 MB output (8x partial-line write-back
// amplification + RFO fetches, visible in FETCH 37 MB vs 16 MB inputs).
// Transposed: each wave's 32 stores fully dirty one 128B line; each block
// writes 512B contiguous. Predicted: WRITE 32.8 -> ~4-5 MB, FETCH -> ~25.
// R16 lesson: occupancy is pinned ~31% regardless of LDS/VGPR — freeing
// resources is not a lever; only schedule restructuring (8-phase) is.
__global__ __launch_bounds__(256) void maxgemm_kernel(
    const unsigned char* __restrict__ Afp8,
    const unsigned char* __restrict__ Nfp8,
    float* __restrict__ partial)   // [128][BS]: stripe-major (transposed!)
{
    __shared__ unsigned char As[BM * BKB];
    __shared__ unsigned char Bs[BN * BKB];

    const int tid  = threadIdx.x;
    const int lane = tid & 63;
    const int w    = tid >> 6;
    const int rowBase = blockIdx.y * BM;
    const int colBase = blockIdx.x * BN;

    const int lrow = lane >> 3;                      // 0..7: row in 8-row slab
    const int gcol = ((lane & 7) ^ lrow) * 16;       // swizzled 16B chunk (bytes)

    const unsigned char* Ag = Afp8 + (size_t)rowBase * DIM;
    const unsigned char* Bg = Nfp8 + (size_t)colBase * DIM;

    const int q2   = (lane >> 4) * 2;                // first 16B chunk of quad
    const int arow = w * 32 + (lane & 15);           // + i*16, i=0..1
    const int brow = (lane & 15);                    // + j*16, j=0..3
    const int aoff = arow * BKB + ((q2 ^ (arow & 7)) << 4);
    const int boff = brow * BKB + ((q2 ^ (brow & 7)) << 4);

    f32x4 acc[2][4];
    #pragma unroll
    for (int i = 0; i < 2; i++)
        #pragma unroll
        for (int j = 0; j < 4; j++)
            acc[i][j] = (f32x4){0.f, 0.f, 0.f, 0.f};

    for (int k0 = 0; k0 < DIM; k0 += BKB) {
        __syncthreads();  // prior iter's LDS reads done
        #pragma unroll
        for (int c = 0; c < 4; c++) {               // A: 4 slabs of 8 rows
            const int r0 = (w * 4 + c) * 8;
            __builtin_amdgcn_global_load_lds(
                (const __attribute__((address_space(1))) void*)
                    (Ag + (size_t)(r0 + lrow) * DIM + k0 + gcol),
                (__attribute__((address_space(3))) void*)(As + r0 * BKB),
                16, 0, 0);
        }
        #pragma unroll
        for (int s = 0; s < 2; s++) {               // B: 2 slabs of 8 rows
            const int r0 = (w * 2 + s) * 8;
            __builtin_amdgcn_global_load_lds(
                (const __attribute__((address_space(1))) void*)
                    (Bg + (size_t)(r0 + lrow) * DIM + k0 + gcol),
                (__attribute__((address_space(3))) void*)(Bs + r0 * BKB),
                16, 0, 0);
        }
        __syncthreads();  // vmcnt drained by barrier semantics

        int8v bf[4];
        #pragma unroll
        for (int j = 0; j < 4; j++)
            bf[j] = ld_frag(Bs, boff + j * 16 * BKB);

        #pragma unroll
        for (int i = 0; i < 2; i++) {
            const int8v a = ld_frag(As, aoff + i * 16 * BKB);
            #pragma unroll
            for (int j = 0; j < 4; j++)
                acc[i][j] = __builtin_amdgcn_mfma_scale_f32_16x16x128_f8f6f4(
                    a, bf[j], acc[i][j],
                    0, 0,               // cbsz=FP8(e4m3), blgp=FP8(e4m3)
                    0, 0x7F7F7F7F,      // opselA, scaleA = 1.0
                    0, 0x7F7F7F7F);     // opselB, scaleB = 1.0
        }
    }

    // Epilogue: per-row max over this block's 64 columns (all in this wave).
    // C/D layout (m89/m91): col = lane&15, row = (lane>>4)*4 + reg.
    // Transposed store: wave w's 32 rows land in ONE contiguous 128B line
    // of partial[stripe][...] — fully-dirty lines, no write amplification.
    const int stripe = blockIdx.x;
    #pragma unroll
    for (int i = 0; i < 2; i++) {
        #pragma unroll
        for (int r = 0; r < 4; r++) {
            float v = fmaxf(fmaxf(acc[i][0][r], acc[i][1][r]),
                            fmaxf(acc[i][2][r], acc[i][3][r]));
            v = fmaxf(v, __shfl_xor(v, 1));
            v = fmaxf(v, __shfl_xor(v, 2));
            v = fmaxf(v, __shfl_xor(v, 4));
            v = fmaxf(v, __shfl_xor(v, 8));
            if ((lane & 15) == 0) {
                const int row = rowBase + w * 32 + i * 16 + (lane >> 4) * 4 + r;
                partial[(size_t)stripe * BS + row] = v;   // = 256 * cos
            }
        }
    }
}

// ---------------- Kernel 3: stripe-max -> loss terms -> per-block partials --
// R17: rewritten for [stripe][row] layout. One thread per row; 128 fully
// coalesced stripe-loads (1KB per block per iter); NO inner-loop shfl.
__global__ __launch_bounds__(256) void reduce_kernel(
    const float* __restrict__ partial,   // [128][BS]
    const float* __restrict__ posdist,
    float* __restrict__ blockpart)       // [32][3]
{
    const int tid = threadIdx.x;
    const int gid = blockIdx.x * 256 + tid;   // row this thread owns

    float m = -1e30f;
    #pragma unroll 8
    for (int s = 0; s < 128; s++)
        m = fmaxf(m, partial[(size_t)s * BS + gid]);

    // m = 256*cos  ->  hard = (2 - 2*cos)/T = (2 - m/128)*TINV
    const float hard = (2.0f - 2.0f * m * INV_QSQ) * TINV;
    const float pos  = posdist[gid];
    float sloss = fmaxf(MARGIN + pos - hard, 0.0f);
    float spos  = pos;
    float shard = hard;

    #pragma unroll
    for (int off = 1; off < 64; off <<= 1) {
        sloss += __shfl_xor(sloss, off);
        spos  += __shfl_xor(spos,  off);
        shard += __shfl_xor(shard, off);
    }

    __shared__ float red[4][3];
    const int lane = tid & 63, w = tid >> 6;
    if (lane == 0) { red[w][0] = sloss; red[w][1] = spos; red[w][2] = shard; }
    __syncthreads();
    if (tid == 0) {
        #pragma unroll
        for (int k = 0; k < 3; k++)
            blockpart[blockIdx.x * 3 + k] =
                red[0][k] + red[1][k] + red[2][k] + red[3][k];
    }
}

// ---------------- Kernel 4: finalize means (one wave, no atomics) -----------
__global__ __launch_bounds__(64) void finalize_kernel(
    const float* __restrict__ blockpart,   // [32][3]
    float* __restrict__ out)
{
    const int lane = threadIdx.x;
    float a = 0.f, b = 0.f, c = 0.f;
    if (lane < 32) {
        a = blockpart[lane * 3 + 0];
        b = blockpart[lane * 3 + 1];
        c = blockpart[lane * 3 + 2];
    }
    #pragma unroll
    for (int off = 1; off < 64; off <<= 1) {
        a += __shfl_xor(a, off);
        b += __shfl_xor(b, off);
        c += __shfl_xor(c, off);
    }
    if (lane == 0) {
        const float inv = 1.0f / (float)BS;
        out[0] = a * inv;
        out[1] = b * inv;
        out[2] = c * inv;
    }
}

extern "C" void kernel_launch(void* const* d_in, const int* in_sizes, int n_in,
                              void* d_out, int out_size, void* d_ws, size_t ws_size,
                              hipStream_t stream) {
    const float* feat = (const float*)d_in[0];
    char* ws = (char*)d_ws;

    // ws layout: Afp8 8MiB | Nfp8 8MiB | partial 4MiB | posdist 32KiB | blockpart
    unsigned char* Afp8      = (unsigned char*)ws;
    unsigned char* Nfp8      = (unsigned char*)(ws + ((size_t)8 << 20));
    float*         partial   = (float*)(ws + ((size_t)16 << 20));
    float*         posdist   = (float*)(ws + ((size_t)20 << 20));
    float*         blockpart = (float*)(ws + ((size_t)20 << 20) + 32768);

    normalize_kernel<<<BS / 4, 256, 0, stream>>>(feat, Afp8, Nfp8, posdist);

    maxgemm_kernel<<<dim3(BS / BN, BS / BM), 256, 0, stream>>>(Afp8, Nfp8, partial);

    reduce_kernel<<<BS / 256, 256, 0, stream>>>(partial, posdist, blockpart);
    finalize_kernel<<<1, 64, 0, stream>>>(blockpart, (float*)d_out);
}

// Round 8
// 263.414 us; speedup vs baseline: 3.0923x; 1.0114x over previous
//
#include <hip/hip_runtime.h>

#define BS   8192
#define DIM  1024
#define TINV 10.0f    // 1 / TEMPERATURE
#define MARGIN 1.0f   // max(0.01, 1.0 - 0.1*0.0)

#define BM  128
#define BN  64
#define BKB 128       // fp8 K-bytes per staging iteration (16x16x128 MFMA)
#define NT  (DIM / BKB)   // 8 K-tiles

// fp8 values are the normalized elements scaled by 16 -> dot = 256 * cos
#define QSCALE   16.0f
#define INV_QSQ  (1.0f / 256.0f)

typedef __attribute__((ext_vector_type(4))) float f32x4;
typedef __attribute__((ext_vector_type(4))) int   int4v;
typedef __attribute__((ext_vector_type(8))) int   int8v;

// ---------------- Kernel 1: L2-normalize rows, emit fp8(e4m3,x16) + posdist -
// (unchanged — one wave per row, pure shfl reduction)
__global__ __launch_bounds__(256) void normalize_kernel(
    const float* __restrict__ feat,
    unsigned char* __restrict__ Afp8,
    unsigned char* __restrict__ Nfp8,
    float* __restrict__ posdist)
{
    const int lane = threadIdx.x & 63;
    const int row  = blockIdx.x * 4 + (threadIdx.x >> 6);   // wave = row

    const float4* fo = (const float4*)(feat + (size_t)row * DIM);
    const float4* fp = (const float4*)(feat + (size_t)(BS + row) * DIM);
    const float4* fn = (const float4*)(feat + (size_t)(2 * BS + row) * DIM);

    float4 o[4], p[4], n[4];
    #pragma unroll
    for (int k = 0; k < 4; k++) {
        o[k] = fo[lane + 64 * k];
        p[k] = fp[lane + 64 * k];
        n[k] = fn[lane + 64 * k];
    }

    float so = 0.f, sp = 0.f, sn = 0.f;
    #pragma unroll
    for (int k = 0; k < 4; k++) {
        so += o[k].x*o[k].x + o[k].y*o[k].y + o[k].z*o[k].z + o[k].w*o[k].w;
        sp += p[k].x*p[k].x + p[k].y*p[k].y + p[k].z*p[k].z + p[k].w*p[k].w;
        sn += n[k].x*n[k].x + n[k].y*n[k].y + n[k].z*n[k].z + n[k].w*n[k].w;
    }
    #pragma unroll
    for (int off = 1; off < 64; off <<= 1) {
        so += __shfl_xor(so, off);
        sp += __shfl_xor(sp, off);
        sn += __shfl_xor(sn, off);
    }

    const float io  = 1.0f / fmaxf(sqrtf(so), 1e-12f);
    const float ip  = 1.0f / fmaxf(sqrtf(sp), 1e-12f);
    const float in_ = 1.0f / fmaxf(sqrtf(sn), 1e-12f);

    int* Ar = (int*)(Afp8 + (size_t)row * DIM);
    int* Nr = (int*)(Nfp8 + (size_t)row * DIM);

    float d = 0.f;
    #pragma unroll
    for (int k = 0; k < 4; k++) {
        float ax = o[k].x*io, ay = o[k].y*io, az = o[k].z*io, aw = o[k].w*io;
        float nx = n[k].x*in_, ny = n[k].y*in_, nz = n[k].z*in_, nw = n[k].w*in_;
        int pa = __builtin_amdgcn_cvt_pk_fp8_f32(ax*QSCALE, ay*QSCALE, 0, false);
        pa     = __builtin_amdgcn_cvt_pk_fp8_f32(az*QSCALE, aw*QSCALE, pa, true);
        int pn = __builtin_amdgcn_cvt_pk_fp8_f32(nx*QSCALE, ny*QSCALE, 0, false);
        pn     = __builtin_amdgcn_cvt_pk_fp8_f32(nz*QSCALE, nw*QSCALE, pn, true);
        Ar[lane + 64 * k] = pa;      // coalesced 4B stores
        Nr[lane + 64 * k] = pn;
        float dx = ax - p[k].x*ip, dy = ay - p[k].y*ip;
        float dz = az - p[k].z*ip, dw = aw - p[k].w*ip;
        d += dx*dx + dy*dy + dz*dz + dw*dw;
    }
    #pragma unroll
    for (int off = 1; off < 64; off <<= 1) d += __shfl_xor(d, off);
    if (lane == 0) posdist[row] = d * TINV;
}

// Load one 32B fragment from swizzled LDS: lo chunk at `off`, hi at off^16
// (chunk parity: (q2+1)^x == (q2^x)^1 for even q2). Union avoids repack.
__device__ __forceinline__ int8v ld_frag(const unsigned char* __restrict__ p,
                                         int off) {
    union { int8v v; struct { int4v lo, hi; } s; } u;
    u.s.lo = *(const int4v*)(p + off);
    u.s.hi = *(const int4v*)(p + (off ^ 16));
    return u.v;
}

// ---------------- Kernel 2: MX-fp8 16x16x128 MFMA max-GEMM (R18) ------------
// R18 = R17 (R9 compute + transposed partial, WRITE fix confirmed -28 MB)
// with the T3+T4 COUNTED-VMCNT pipeline: LDS dbuf, raw s_barrier, and
// s_waitcnt vmcnt(6) — never vmcnt(0) — in the main loop. R12's dbuf was
// neutral because __syncthreads' semantics force a full vmcnt(0) drain at
// every barrier (m99/m100); the m218 A/B showed counted-vs-drain0 IS the
// pipeline gain (+38-73%), m233 showed the drain is ~72% of the 2-phase
// critical path. Here tile t+2's 6 global_load_lds ride in flight across
// both barriers while tile t computes; vmcnt(6) retires only tile t+1's.
// Correctness: wave w's A-frag rows == rows wave w stages (self-dep); B is
// cross-wave -> each wave waits vmcnt for its OWN loads, then s_barrier
// makes them collectively visible. ds_reads stay C++-level (compiler
// manages lgkmcnt); ""-memory fences pin LDS ops to their barrier side.
__global__ __launch_bounds__(256) void maxgemm_kernel(
    const unsigned char* __restrict__ Afp8,
    const unsigned char* __restrict__ Nfp8,
    float* __restrict__ partial)   // [128][BS]: stripe-major (transposed)
{
    __shared__ unsigned char As[2][BM * BKB];   // 2 x 16 KiB
    __shared__ unsigned char Bs[2][BN * BKB];   // 2 x  8 KiB

    const int tid  = threadIdx.x;
    const int lane = tid & 63;
    const int w    = tid >> 6;
    const int rowBase = blockIdx.y * BM;
    const int colBase = blockIdx.x * BN;

    const int lrow = lane >> 3;                      // 0..7: row in 8-row slab
    const int gcol = ((lane & 7) ^ lrow) * 16;       // swizzled 16B chunk (bytes)

    const unsigned char* Ag = Afp8 + (size_t)rowBase * DIM;
    const unsigned char* Bg = Nfp8 + (size_t)colBase * DIM;

    const int q2   = (lane >> 4) * 2;                // first 16B chunk of quad
    const int arow = w * 32 + (lane & 15);           // + i*16, i=0..1
    const int brow = (lane & 15);                    // + j*16, j=0..3
    const int aoff = arow * BKB + ((q2 ^ (arow & 7)) << 4);
    const int boff = brow * BKB + ((q2 ^ (brow & 7)) << 4);

    f32x4 acc[2][4];
    #pragma unroll
    for (int i = 0; i < 2; i++)
        #pragma unroll
        for (int j = 0; j < 4; j++)
            acc[i][j] = (f32x4){0.f, 0.f, 0.f, 0.f};

// 6 global_load_lds: 4 A-slabs + 2 B-slabs of 8 rows each, per wave.
#define STAGE(BUF, T)                                                         \
    {                                                                         \
        const int k0_ = (T) * BKB;                                            \
        _Pragma("unroll")                                                     \
        for (int c = 0; c < 4; c++) {                                         \
            const int r0 = (w * 4 + c) * 8;                                   \
            __builtin_amdgcn_global_load_lds(                                 \
                (const __attribute__((address_space(1))) void*)               \
                    (Ag + (size_t)(r0 + lrow) * DIM + k0_ + gcol),            \
                (__attribute__((address_space(3))) void*)(As[BUF] + r0 * BKB),\
                16, 0, 0);                                                    \
        }                                                                     \
        _Pragma("unroll")                                                     \
        for (int s = 0; s < 2; s++) {                                         \
            const int r0 = (w * 2 + s) * 8;                                   \
            __builtin_amdgcn_global_load_lds(                                 \
                (const __attribute__((address_space(1))) void*)               \
                    (Bg + (size_t)(r0 + lrow) * DIM + k0_ + gcol),            \
                (__attribute__((address_space(3))) void*)(Bs[BUF] + r0 * BKB),\
                16, 0, 0);                                                    \
        }                                                                     \
    }

    // ---- prologue: tiles 0 and 1 in flight; wait only for tile 0 ----
    STAGE(0, 0);
    STAGE(1, 1);
    asm volatile("s_waitcnt vmcnt(6)" ::: "memory");  // tile0's 6 landed (mine)
    __builtin_amdgcn_s_barrier();                     // everyone's tile0 landed
    asm volatile("" ::: "memory");

    int cur = 0;
    #pragma unroll
    for (int t = 0; t < NT; ++t, cur ^= 1) {
        // ---- compute tile t from buf[cur]; buf[cur^1] = t+1 in flight ----
        int8v bf[4];
        #pragma unroll
        for (int j = 0; j < 4; j++)
            bf[j] = ld_frag(Bs[cur], boff + j * 16 * BKB);

        #pragma unroll
        for (int i = 0; i < 2; i++) {
            const int8v a = ld_frag(As[cur], aoff + i * 16 * BKB);
            #pragma unroll
            for (int j = 0; j < 4; j++)
                acc[i][j] = __builtin_amdgcn_mfma_scale_f32_16x16x128_f8f6f4(
                    a, bf[j], acc[i][j],
                    0, 0,               // cbsz=FP8(e4m3), blgp=FP8(e4m3)
                    0, 0x7F7F7F7F,      // opselA, scaleA = 1.0
                    0, 0x7F7F7F7F);     // opselB, scaleB = 1.0
        }

        asm volatile("" ::: "memory");
        __builtin_amdgcn_s_barrier();      // all waves done reading buf[cur]
        asm volatile("" ::: "memory");

        if (t + 2 < NT) {
            STAGE(cur, t + 2);             // refill freed buffer; 12 in flight
            asm volatile("s_waitcnt vmcnt(6)" ::: "memory"); // t+1's 6 landed
        } else {
            asm volatile("s_waitcnt vmcnt(0)" ::: "memory"); // tail drain
        }
        __builtin_amdgcn_s_barrier();      // everyone's t+1 landed
        asm volatile("" ::: "memory");
    }
#undef STAGE

    // Epilogue: per-row max over this block's 64 columns (all in this wave).
    // C/D layout (m89/m91): col = lane&15, row = (lane>>4)*4 + reg.
    // Transposed store: wave w's 32 rows fully dirty one 128B line.
    const int stripe = blockIdx.x;
    #pragma unroll
    for (int i = 0; i < 2; i++) {
        #pragma unroll
        for (int r = 0; r < 4; r++) {
            float v = fmaxf(fmaxf(acc[i][0][r], acc[i][1][r]),
                            fmaxf(acc[i][2][r], acc[i][3][r]));
            v = fmaxf(v, __shfl_xor(v, 1));
            v = fmaxf(v, __shfl_xor(v, 2));
            v = fmaxf(v, __shfl_xor(v, 4));
            v = fmaxf(v, __shfl_xor(v, 8));
            if ((lane & 15) == 0) {
                const int row = rowBase + w * 32 + i * 16 + (lane >> 4) * 4 + r;
                partial[(size_t)stripe * BS + row] = v;   // = 256 * cos
            }
        }
    }
}

// ---------------- Kernel 3: stripe-max -> loss terms -> per-block partials --
// [stripe][row] layout: one thread per row; 128 coalesced stripe-loads.
__global__ __launch_bounds__(256) void reduce_kernel(
    const float* __restrict__ partial,   // [128][BS]
    const float* __restrict__ posdist,
    float* __restrict__ blockpart)       // [32][3]
{
    const int tid = threadIdx.x;
    const int gid = blockIdx.x * 256 + tid;   // row this thread owns

    float m = -1e30f;
    #pragma unroll 8
    for (int s = 0; s < 128; s++)
        m = fmaxf(m, partial[(size_t)s * BS + gid]);

    // m = 256*cos  ->  hard = (2 - 2*cos)/T = (2 - m/128)*TINV
    const float hard = (2.0f - 2.0f * m * INV_QSQ) * TINV;
    const float pos  = posdist[gid];
    float sloss = fmaxf(MARGIN + pos - hard, 0.0f);
    float spos  = pos;
    float shard = hard;

    #pragma unroll
    for (int off = 1; off < 64; off <<= 1) {
        sloss += __shfl_xor(sloss, off);
        spos  += __shfl_xor(spos,  off);
        shard += __shfl_xor(shard, off);
    }

    __shared__ float red[4][3];
    const int lane = tid & 63, w = tid >> 6;
    if (lane == 0) { red[w][0] = sloss; red[w][1] = spos; red[w][2] = shard; }
    __syncthreads();
    if (tid == 0) {
        #pragma unroll
        for (int k = 0; k < 3; k++)
            blockpart[blockIdx.x * 3 + k] =
                red[0][k] + red[1][k] + red[2][k] + red[3][k];
    }
}

// ---------------- Kernel 4: finalize means (one wave, no atomics) -----------
__global__ __launch_bounds__(64) void finalize_kernel(
    const float* __restrict__ blockpart,   // [32][3]
    float* __restrict__ out)
{
    const int lane = threadIdx.x;
    float a = 0.f, b = 0.f, c = 0.f;
    if (lane < 32) {
        a = blockpart[lane * 3 + 0];
        b = blockpart[lane * 3 + 1];
        c = blockpart[lane * 3 + 2];
    }
    #pragma unroll
    for (int off = 1; off < 64; off <<= 1) {
        a += __shfl_xor(a, off);
        b += __shfl_xor(b, off);
        c += __shfl_xor(c, off);
    }
    if (lane == 0) {
        const float inv = 1.0f / (float)BS;
        out[0] = a * inv;
        out[1] = b * inv;
        out[2] = c * inv;
    }
}

extern "C" void kernel_launch(void* const* d_in, const int* in_sizes, int n_in,
                              void* d_out, int out_size, void* d_ws, size_t ws_size,
                              hipStream_t stream) {
    const float* feat = (const float*)d_in[0];
    char* ws = (char*)d_ws;

    // ws layout: Afp8 8MiB | Nfp8 8MiB | partial 4MiB | posdist 32KiB | blockpart
    unsigned char* Afp8      = (unsigned char*)ws;
    unsigned char* Nfp8      = (unsigned char*)(ws + ((size_t)8 << 20));
    float*         partial   = (float*)(ws + ((size_t)16 << 20));
    float*         posdist   = (float*)(ws + ((size_t)20 << 20));
    float*         blockpart = (float*)(ws + ((size_t)20 << 20) + 32768);

    normalize_kernel<<<BS / 4, 256, 0, stream>>>(feat, Afp8, Nfp8, posdist);

    maxgemm_kernel<<<dim3(BS / BN, BS / BM), 256, 0, stream>>>(Afp8, Nfp8, partial);

    reduce_kernel<<<BS / 256, 256, 0, stream>>>(partial, posdist, blockpart);
    finalize_kernel<<<1, 64, 0, stream>>>(blockpart, (float*)d_out);
}